// Round 6
// baseline (2952.465 us; speedup 1.0000x reference)
//
#include <hip/hip_runtime.h>

// BaseRNN B=64,S=512,H=E=512,L=2 — persistent kernel, R16.
// R15 (R10 protocol + latched poll + s_sleep + early publish): 2918 us, best.
//   FETCH 113->72MB vs R11 (latch removed poll traffic). WRITE still 137MB =
//   ALL ring stores reach HBM (ring-513 never reuses a slot -> MALL must
//   write back 131MB/call; the vmcnt(0) drain sits behind that backpressure).
// R16 single change (H4 test): ring 513 -> 8. Working set 2MB, MALL-resident,
//   dirty lines recycled in place; HBM writeback eliminated. WAR throttle
//   (already in the poll: lanes 16-31 of l0) re-derived safe for ring=8:
//   overwrite of h0[q] at phase q+8 gated by F1>=q+1 which proves l1's read
//   of h0[q] completed; l1 peers are lockstep so h1 distance-8 reuse is safe;
//   steady-state l0 lead ~1 < 7 so the throttle never binds.
// Predicted: WRITE 137->~5MB (engagement signature); H4-true: dur -> ~2.6ms;
// flat dur + collapsed WRITE falsifies H4 -> next: sync degree / poll venue.

#define BATCH 64
#define SEQ   512
#define HID   512
#define NTHR  256
#define CB    8
#define ROWS  32
#define SLOT  (BATCH * HID)     // floats per ring slot (128KB)
#define RING  8

typedef unsigned int u32;

__device__ __forceinline__ float dot4(const float4 a, const float4 b) {
  return a.x * b.x + a.y * b.y + a.z * b.z + a.w * b.w;
}
__device__ __forceinline__ float2 ld2(const double* p) {   // sc1 8B load
  const double d = __hip_atomic_load(p, __ATOMIC_RELAXED, __HIP_MEMORY_SCOPE_AGENT);
  return __builtin_bit_cast(float2, d);
}
__device__ __forceinline__ void st2(double* p, float2 v) { // sc1 8B store
  __hip_atomic_store(p, __builtin_bit_cast(double, v),
                     __ATOMIC_RELAXED, __HIP_MEMORY_SCOPE_AGENT);
}
__device__ __forceinline__ float tanh_fast(float x) {
  const float a = fabsf(x);
  const float e = __expf(-2.0f * a);
  const float t = (1.0f - e) * __builtin_amdgcn_rcpf(1.0f + e);
  return copysignf(t, x);
}
#define WAIT_VM0() asm volatile("s_waitcnt vmcnt(0)" ::: "memory")

#define RSTEP(D, N)                                                   \
  {                                                                   \
    const bool hi = (lane & (D)) != 0;                                \
    _Pragma("unroll")                                                 \
    for (int a = 0; a < (N); ++a) {                                   \
      const float keep = hi ? v[a + (N)] : v[a];                      \
      const float send = hi ? v[a] : v[a + (N)];                      \
      v[a] = keep + __shfl_xor(send, (D));                            \
    }                                                                 \
  }

__global__ __launch_bounds__(NTHR, 1) void rnn_persistent(
    const int* __restrict__ x, const int* __restrict__ lengths,
    const float* __restrict__ emb,
    const float* __restrict__ W_ih, const float* __restrict__ W_hh,
    const float* __restrict__ b_ih, const float* __restrict__ b_hh,
    float* __restrict__ out,
    float* h0r, float* h1r, u32* F, int ring)
{
  __shared__ __align__(16) float Xa[CB][HID];        // 16KB
  __shared__ __align__(16) float Xb[CB][HID];        // 16KB
  __shared__ __align__(16) float Xpart[CB][ROWS][4]; // 4KB
  __shared__ int Lens[CB];

  const int wg    = blockIdx.x;
  const int tid   = threadIdx.x;
  const int dom   = wg & 7;
  const int q     = wg >> 3;
  const int layer = q >> 4;
  const int rg    = q & 15;
  const int bbase = dom * CB;
  const int jbase = rg * ROWS;
  const int tj    = tid >> 6;
  const int lane  = tid & 63;

  // flags: entry (dom,layer,rg) on its own 128B line; value = #slots written
  u32* Fown = F + ((dom * 2 + layer) * 16 + rg) * 32;
  u32* F0   = F + ((dom * 2 + 0) * 16) * 32;   // + i*32
  u32* F1   = F + ((dom * 2 + 1) * 16) * 32;

  // ---- weights in registers: 8 j x (2 float4 k) x 2 mats = 128 VGPRs ----
  float4 wa[2][8], wb[2][8];
  {
    const float* WA = W_ih + layer * (HID * HID);
    const float* WB = W_hh + layer * (HID * HID);
    #pragma unroll
    for (int ji = 0; ji < 8; ++ji) {
      const int j = jbase + tj * 8 + ji;
      #pragma unroll
      for (int i = 0; i < 2; ++i) {
        const int k = i * 256 + 4 * lane;
        wa[i][ji] = *(const float4*)&WA[j * HID + k];
        wb[i][ji] = *(const float4*)&WB[j * HID + k];
      }
    }
  }
  if (tid < CB) Lens[tid] = lengths[bbase + tid];
  __syncthreads();
  int maxlen = Lens[0];
  #pragma unroll
  for (int i = 1; i < CB; ++i) maxlen = max(maxlen, Lens[i]);
  const int P     = maxlen;                       // 1..512
  const int pl0   = (P < SEQ) ? P : (SEQ - 1);    // l0's last active phase
  const int plast = layer ? P : pl0;
  int lm[4];                                      // group liveness bounds
  #pragma unroll
  for (int g = 0; g < 4; ++g) lm[g] = max(Lens[2 * g], Lens[2 * g + 1]);

  float4 bias4 = make_float4(0.f, 0.f, 0.f, 0.f);
  if (tid < 64) {
    const int jq = jbase + (tid & 7) * 4;
    bias4.x = b_ih[layer * HID + jq + 0] + b_hh[layer * HID + jq + 0];
    bias4.y = b_ih[layer * HID + jq + 1] + b_hh[layer * HID + jq + 1];
    bias4.z = b_ih[layer * HID + jq + 2] + b_hh[layer * HID + jq + 2];
    bias4.w = b_ih[layer * HID + jq + 3] + b_hh[layer * HID + jq + 3];
  }

  // ---- initial emb prefetch (t=0, l0) ----
  float4 pf[4];
  if (layer == 0) {
    #pragma unroll
    for (int i = 0; i < 4; ++i) {
      const int u = tid + NTHR * i;
      const int r = u >> 7, c = (u & 127) * 4;
      const int tok = x[(bbase + r) * SEQ];
      pf[i] = *(const float4*)&emb[(size_t)tok * HID + c];
    }
  }

  int cur = 0, prev = ring - 1;   // p % ring, (p-1) % ring

  for (int p = 0; p <= P; ++p) {
    const bool active = layer ? (p >= 1) : (p < SEQ);
    const int  wr0    = (cur + 1 == ring) ? 0 : (cur + 1);

    if (active) {
      const int t = layer ? (p - 1) : p;

      // ---- stage: sc1 ring loads -> LDS ----
      if (layer == 0) {
        const double* src = (const double*)(h0r) + (size_t)cur * (SLOT / 2);
        float2 tv[8];
        #pragma unroll
        for (int i = 0; i < 8; ++i) {
          const int u = tid + NTHR * i;
          tv[i] = ld2(&src[(size_t)(bbase + (u >> 8)) * 256 + (u & 255)]);
        }
        #pragma unroll
        for (int i = 0; i < 8; ++i) {
          const int u = tid + NTHR * i;
          *(float2*)&Xb[u >> 8][(u & 255) * 2] = tv[i];
        }
        #pragma unroll
        for (int i = 0; i < 4; ++i) {
          const int u = tid + NTHR * i;
          *(float4*)&Xa[u >> 7][(u & 127) * 4] = pf[i];
        }
      } else {
        const double* srcB = (const double*)(h1r) + (size_t)prev * (SLOT / 2);
        const double* srcA = (const double*)(h0r) + (size_t)cur  * (SLOT / 2);
        float2 tb[8], ta[8];
        #pragma unroll
        for (int i = 0; i < 8; ++i) {
          const int u = tid + NTHR * i;
          tb[i] = ld2(&srcB[(size_t)(bbase + (u >> 8)) * 256 + (u & 255)]);
        }
        #pragma unroll
        for (int i = 0; i < 8; ++i) {
          const int u = tid + NTHR * i;
          ta[i] = ld2(&srcA[(size_t)(bbase + (u >> 8)) * 256 + (u & 255)]);
        }
        #pragma unroll
        for (int i = 0; i < 8; ++i) {
          const int u = tid + NTHR * i;
          *(float2*)&Xb[u >> 8][(u & 255) * 2] = tb[i];
          *(float2*)&Xa[u >> 8][(u & 255) * 2] = ta[i];
        }
      }
      __syncthreads();

      // ---- compute: 4 groups, unroll 2; skip fully-frozen groups ----
      #pragma unroll 2
      for (int g = 0; g < 4; ++g) {
        if (t >= lm[g]) continue;            // wave-uniform (Lens shared)
        float v[16];
        #pragma unroll
        for (int o = 0; o < 16; ++o) v[o] = 0.f;
        #pragma unroll
        for (int bi = 0; bi < 2; ++bi) {
          const int b = g * 2 + bi;
          const float4 xa0 = *(const float4*)&Xa[b][4 * lane];
          const float4 xa1 = *(const float4*)&Xa[b][256 + 4 * lane];
          const float4 xb0 = *(const float4*)&Xb[b][4 * lane];
          const float4 xb1 = *(const float4*)&Xb[b][256 + 4 * lane];
          #pragma unroll
          for (int ji = 0; ji < 8; ++ji) {
            v[bi * 8 + ji] += dot4(wa[0][ji], xa0) + dot4(wa[1][ji], xa1)
                            + dot4(wb[0][ji], xb0) + dot4(wb[1][ji], xb1);
          }
        }
        RSTEP(32, 8)
        RSTEP(16, 4)
        RSTEP(8, 2)
        RSTEP(4, 1)
        const int b_o = g * 2 + (lane >> 5);
        const int j_o = tj * 8 + ((lane >> 2) & 7);
        Xpart[b_o][j_o][lane & 3] = v[0];
      }
      __syncthreads();

      // ---- finalize: sum partials, fast tanh, mask, sc1 ring store ----
      if (tid < 64) {
        const int b = tid >> 3, jq = (tid & 7) * 4;
        const float4 hb = *(const float4*)&Xb[b][jbase + jq];
        const bool live = (t < Lens[b]);
        float4 r = hb;
        if (live) {
          const float4 p0 = *(const float4*)&Xpart[b][jq + 0][0];
          const float4 p1 = *(const float4*)&Xpart[b][jq + 1][0];
          const float4 p2 = *(const float4*)&Xpart[b][jq + 2][0];
          const float4 p3 = *(const float4*)&Xpart[b][jq + 3][0];
          r.x = tanh_fast(p0.x + p0.y + p0.z + p0.w + bias4.x);
          r.y = tanh_fast(p1.x + p1.y + p1.z + p1.w + bias4.y);
          r.z = tanh_fast(p2.x + p2.y + p2.z + p2.w + bias4.z);
          r.w = tanh_fast(p3.x + p3.y + p3.z + p3.w + bias4.w);
        }
        double* dst = layer ? ((double*)h1r + (size_t)cur * (SLOT / 2))
                            : ((double*)h0r + (size_t)wr0 * (SLOT / 2));
        const size_t di = (size_t)(bbase + b) * 256 + ((jbase + jq) >> 1);
        st2(&dst[di],     make_float2(r.x, r.y));
        st2(&dst[di + 1], make_float2(r.z, r.w));
        if (p == plast) {   // fused epilogue: own tile = own output
          if (layer == 0) {
            *(float4*)&out[32768 + (size_t)(bbase + b) * 1024 + jbase + jq] = r;
          } else {
            *(float4*)&out[(size_t)(bbase + b) * 512 + jbase + jq] = r;
            *(float4*)&out[32768 + (size_t)(bbase + b) * 1024 + 512 + jbase + jq] = r;
          }
        }
      }
    }

    // ---- exchange: drain -> EARLY flag publish -> prefetch -> detect ----
    // Ring data is written and drained exclusively by wave 0, so the flag
    // publish needs only wave0's vmcnt(0) — not the barrier join.
    WAIT_VM0();
    if (tid == 0 && active)   // l0 publishes p+1 slots, l1 publishes p
      __hip_atomic_store(Fown, (u32)(layer ? p : (p + 1)),
                         __ATOMIC_RELAXED, __HIP_MEMORY_SCOPE_AGENT);
    __syncthreads();
    const int np = p + 1;
    if (layer == 0 && np <= plast) {
      #pragma unroll
      for (int i = 0; i < 4; ++i) {
        const int u = tid + NTHR * i;
        const int r = u >> 7, c = (u & 127) * 4;
        const int tok = x[(bbase + r) * SEQ + np];
        pf[i] = *(const float4*)&emb[(size_t)tok * HID + c];
      }
    }
    if (np <= P) {
      if (tid < 64) {
        u32* fp  = Fown;            // dummy for idle lanes (always valid)
        u32  tgt = 0;
        bool ok  = true;            // idle lanes start satisfied
        if (lane < 16) { fp = F0 + lane * 32; tgt = (u32)np; ok = false; }
        else if (lane < 32) {
          if (layer) { fp = F1 + (lane - 16) * 32; tgt = (u32)(np - 1); ok = false; }
          else {
            const int th = np + 1 - ring;   // ring WAR throttle (l0 lead <= ring-1)
            if (th > 0) { fp = F1 + (lane - 16) * 32; tgt = (u32)th; ok = false; }
          }
        }
        // latched poll: a lane stops loading once its peer passed; backoff
        // on failed ballot keeps straggler-poll traffic off the fabric.
        while (true) {
          if (!ok) ok = (__hip_atomic_load(fp, __ATOMIC_RELAXED,
                                           __HIP_MEMORY_SCOPE_AGENT) >= tgt);
          if (__ballot(ok) == ~0ull) break;
          __builtin_amdgcn_s_sleep(1);
        }
      }
      __syncthreads();
    }
    prev = cur; cur = wr0;
  }
}

extern "C" void kernel_launch(void* const* d_in, const int* in_sizes, int n_in,
                              void* d_out, int out_size, void* d_ws, size_t ws_size,
                              hipStream_t stream) {
  (void)in_sizes; (void)n_in; (void)out_size; (void)ws_size;
  const int*   x       = (const int*)d_in[0];
  const int*   lengths = (const int*)d_in[1];
  const float* emb     = (const float*)d_in[2];
  const float* W_ih    = (const float*)d_in[3];
  const float* W_hh    = (const float*)d_in[4];
  const float* b_ih    = (const float*)d_in[5];
  const float* b_hh    = (const float*)d_in[6];
  float* out = (float*)d_out;

  const size_t slotB = (size_t)SLOT * sizeof(float);   // 128KB
  const int ring = RING;                               // 8: MALL-resident, throttled

  float* h0r = (float*)d_ws;
  float* h1r = h0r + (size_t)ring * SLOT;
  u32*   F   = (u32*)(h1r + (size_t)ring * SLOT);

  // zero slot 0 of each ring (h(-1)=0) + flag page; ws re-poisoned each call
  hipMemsetAsync(h0r, 0, slotB, stream);
  hipMemsetAsync(h1r, 0, slotB, stream);
  hipMemsetAsync(F, 0, 32768, stream);

  hipLaunchKernelGGL(rnn_persistent, dim3(256), dim3(NTHR), 0, stream,
                     x, lengths, emb, W_ih, W_hh, b_ih, b_hh, out,
                     h0r, h1r, F, ring);
}

// Round 7
// 2936.049 us; speedup vs baseline: 1.0056x; 1.0056x over previous
//
#include <hip/hip_runtime.h>

// BaseRNN B=64,S=512,H=E=512,L=2 — persistent kernel, R17.
// R16 post-mortem: H4 (writeback backpressure) FALSIFIED — WRITE_SIZE
// byte-identical at ring=8 vs 513 (sc1 stores write through L2 regardless);
// dur flat. Remaining ~4.8us/phase = 4 dependent sc1 hops at ~1us (MALL).
// R17 single change: DUAL-PUBLISHED FLAGS, no probe, no placement assumption.
//  - Producer publishes flag twice after the data drain: sc1 -> F line
//    (proven venue, universal) AND sc0 -> G line (separate 128B line; lands
//    in producer's XCD L2).
//  - Consumer polls G via sc0 (same-XCD: L2-coherent, ~0.2us detect under
//    the measured round-robin wg->XCD mapping where dom=wg&7 is one-XCD);
//    every 4th iteration checks F via sc1 (cross-XCD rescue -> no hang,
//    bounded at today's latency). Flags monotonic; venues never share a
//    line; kernel-launch acquire invalidates stale G lines across calls.
//  - Data path stays sc1 end-to-end: correctness placement-independent.
// Everything else identical to R16 (ring=8, latched poll, s_sleep backoff,
// early publish, fused epilogue, emb prefetch).

#define BATCH 64
#define SEQ   512
#define HID   512
#define NTHR  256
#define CB    8
#define ROWS  32
#define SLOT  (BATCH * HID)     // floats per ring slot (128KB)
#define RING  8

typedef unsigned int u32;

__device__ __forceinline__ float dot4(const float4 a, const float4 b) {
  return a.x * b.x + a.y * b.y + a.z * b.z + a.w * b.w;
}
__device__ __forceinline__ float2 ld2(const double* p) {   // sc1 8B load
  const double d = __hip_atomic_load(p, __ATOMIC_RELAXED, __HIP_MEMORY_SCOPE_AGENT);
  return __builtin_bit_cast(float2, d);
}
__device__ __forceinline__ void st2(double* p, float2 v) { // sc1 8B store
  __hip_atomic_store(p, __builtin_bit_cast(double, v),
                     __ATOMIC_RELAXED, __HIP_MEMORY_SCOPE_AGENT);
}
// sc0 flag ops: bypass L1, serviced by the XCD's L2 (coherent within XCD)
__device__ __forceinline__ u32 ld_flag_sc0(const u32* p) {
  u32 r;
  asm volatile("global_load_dword %0, %1, off sc0\n\ts_waitcnt vmcnt(0)"
               : "=v"(r) : "v"(p) : "memory");
  return r;
}
__device__ __forceinline__ void st_flag_sc0(u32* p, u32 v) {
  asm volatile("global_store_dword %0, %1, off sc0" :: "v"(p), "v"(v) : "memory");
}
__device__ __forceinline__ float tanh_fast(float x) {
  const float a = fabsf(x);
  const float e = __expf(-2.0f * a);
  const float t = (1.0f - e) * __builtin_amdgcn_rcpf(1.0f + e);
  return copysignf(t, x);
}
#define WAIT_VM0() asm volatile("s_waitcnt vmcnt(0)" ::: "memory")

#define RSTEP(D, N)                                                   \
  {                                                                   \
    const bool hi = (lane & (D)) != 0;                                \
    _Pragma("unroll")                                                 \
    for (int a = 0; a < (N); ++a) {                                   \
      const float keep = hi ? v[a + (N)] : v[a];                      \
      const float send = hi ? v[a] : v[a + (N)];                      \
      v[a] = keep + __shfl_xor(send, (D));                            \
    }                                                                 \
  }

__global__ __launch_bounds__(NTHR, 1) void rnn_persistent(
    const int* __restrict__ x, const int* __restrict__ lengths,
    const float* __restrict__ emb,
    const float* __restrict__ W_ih, const float* __restrict__ W_hh,
    const float* __restrict__ b_ih, const float* __restrict__ b_hh,
    float* __restrict__ out,
    float* h0r, float* h1r, u32* F, int ring)
{
  __shared__ __align__(16) float Xa[CB][HID];        // 16KB
  __shared__ __align__(16) float Xb[CB][HID];        // 16KB
  __shared__ __align__(16) float Xpart[CB][ROWS][4]; // 4KB
  __shared__ int Lens[CB];

  const int wg    = blockIdx.x;
  const int tid   = threadIdx.x;
  const int dom   = wg & 7;
  const int q     = wg >> 3;
  const int layer = q >> 4;
  const int rg    = q & 15;
  const int bbase = dom * CB;
  const int jbase = rg * ROWS;
  const int tj    = tid >> 6;
  const int lane  = tid & 63;

  // F: sc1 flag lines (proven venue). G: sc0 flag lines (XCD-L2 venue),
  // DISTINCT 128B lines at +64KB so the two venues never share a line.
  u32* Fown = F + ((dom * 2 + layer) * 16 + rg) * 32;
  u32* F0   = F + ((dom * 2 + 0) * 16) * 32;   // + i*32
  u32* F1   = F + ((dom * 2 + 1) * 16) * 32;
  u32* G    = F + 16384;
  u32* Gown = G + ((dom * 2 + layer) * 16 + rg) * 32;
  u32* G0   = G + ((dom * 2 + 0) * 16) * 32;
  u32* G1   = G + ((dom * 2 + 1) * 16) * 32;

  // ---- weights in registers: 8 j x (2 float4 k) x 2 mats = 128 VGPRs ----
  float4 wa[2][8], wb[2][8];
  {
    const float* WA = W_ih + layer * (HID * HID);
    const float* WB = W_hh + layer * (HID * HID);
    #pragma unroll
    for (int ji = 0; ji < 8; ++ji) {
      const int j = jbase + tj * 8 + ji;
      #pragma unroll
      for (int i = 0; i < 2; ++i) {
        const int k = i * 256 + 4 * lane;
        wa[i][ji] = *(const float4*)&WA[j * HID + k];
        wb[i][ji] = *(const float4*)&WB[j * HID + k];
      }
    }
  }
  if (tid < CB) Lens[tid] = lengths[bbase + tid];
  __syncthreads();
  int maxlen = Lens[0];
  #pragma unroll
  for (int i = 1; i < CB; ++i) maxlen = max(maxlen, Lens[i]);
  const int P     = maxlen;                       // 1..512
  const int pl0   = (P < SEQ) ? P : (SEQ - 1);    // l0's last active phase
  const int plast = layer ? P : pl0;
  int lm[4];                                      // group liveness bounds
  #pragma unroll
  for (int g = 0; g < 4; ++g) lm[g] = max(Lens[2 * g], Lens[2 * g + 1]);

  float4 bias4 = make_float4(0.f, 0.f, 0.f, 0.f);
  if (tid < 64) {
    const int jq = jbase + (tid & 7) * 4;
    bias4.x = b_ih[layer * HID + jq + 0] + b_hh[layer * HID + jq + 0];
    bias4.y = b_ih[layer * HID + jq + 1] + b_hh[layer * HID + jq + 1];
    bias4.z = b_ih[layer * HID + jq + 2] + b_hh[layer * HID + jq + 2];
    bias4.w = b_ih[layer * HID + jq + 3] + b_hh[layer * HID + jq + 3];
  }

  // ---- initial emb prefetch (t=0, l0) ----
  float4 pf[4];
  if (layer == 0) {
    #pragma unroll
    for (int i = 0; i < 4; ++i) {
      const int u = tid + NTHR * i;
      const int r = u >> 7, c = (u & 127) * 4;
      const int tok = x[(bbase + r) * SEQ];
      pf[i] = *(const float4*)&emb[(size_t)tok * HID + c];
    }
  }

  int cur = 0, prev = ring - 1;   // p % ring, (p-1) % ring

  for (int p = 0; p <= P; ++p) {
    const bool active = layer ? (p >= 1) : (p < SEQ);
    const int  wr0    = (cur + 1 == ring) ? 0 : (cur + 1);

    if (active) {
      const int t = layer ? (p - 1) : p;

      // ---- stage: sc1 ring loads -> LDS ----
      if (layer == 0) {
        const double* src = (const double*)(h0r) + (size_t)cur * (SLOT / 2);
        float2 tv[8];
        #pragma unroll
        for (int i = 0; i < 8; ++i) {
          const int u = tid + NTHR * i;
          tv[i] = ld2(&src[(size_t)(bbase + (u >> 8)) * 256 + (u & 255)]);
        }
        #pragma unroll
        for (int i = 0; i < 8; ++i) {
          const int u = tid + NTHR * i;
          *(float2*)&Xb[u >> 8][(u & 255) * 2] = tv[i];
        }
        #pragma unroll
        for (int i = 0; i < 4; ++i) {
          const int u = tid + NTHR * i;
          *(float4*)&Xa[u >> 7][(u & 127) * 4] = pf[i];
        }
      } else {
        const double* srcB = (const double*)(h1r) + (size_t)prev * (SLOT / 2);
        const double* srcA = (const double*)(h0r) + (size_t)cur  * (SLOT / 2);
        float2 tb[8], ta[8];
        #pragma unroll
        for (int i = 0; i < 8; ++i) {
          const int u = tid + NTHR * i;
          tb[i] = ld2(&srcB[(size_t)(bbase + (u >> 8)) * 256 + (u & 255)]);
        }
        #pragma unroll
        for (int i = 0; i < 8; ++i) {
          const int u = tid + NTHR * i;
          ta[i] = ld2(&srcA[(size_t)(bbase + (u >> 8)) * 256 + (u & 255)]);
        }
        #pragma unroll
        for (int i = 0; i < 8; ++i) {
          const int u = tid + NTHR * i;
          *(float2*)&Xb[u >> 8][(u & 255) * 2] = tb[i];
          *(float2*)&Xa[u >> 8][(u & 255) * 2] = ta[i];
        }
      }
      __syncthreads();

      // ---- compute: 4 groups, unroll 2; skip fully-frozen groups ----
      #pragma unroll 2
      for (int g = 0; g < 4; ++g) {
        if (t >= lm[g]) continue;            // wave-uniform (Lens shared)
        float v[16];
        #pragma unroll
        for (int o = 0; o < 16; ++o) v[o] = 0.f;
        #pragma unroll
        for (int bi = 0; bi < 2; ++bi) {
          const int b = g * 2 + bi;
          const float4 xa0 = *(const float4*)&Xa[b][4 * lane];
          const float4 xa1 = *(const float4*)&Xa[b][256 + 4 * lane];
          const float4 xb0 = *(const float4*)&Xb[b][4 * lane];
          const float4 xb1 = *(const float4*)&Xb[b][256 + 4 * lane];
          #pragma unroll
          for (int ji = 0; ji < 8; ++ji) {
            v[bi * 8 + ji] += dot4(wa[0][ji], xa0) + dot4(wa[1][ji], xa1)
                            + dot4(wb[0][ji], xb0) + dot4(wb[1][ji], xb1);
          }
        }
        RSTEP(32, 8)
        RSTEP(16, 4)
        RSTEP(8, 2)
        RSTEP(4, 1)
        const int b_o = g * 2 + (lane >> 5);
        const int j_o = tj * 8 + ((lane >> 2) & 7);
        Xpart[b_o][j_o][lane & 3] = v[0];
      }
      __syncthreads();

      // ---- finalize: sum partials, fast tanh, mask, sc1 ring store ----
      if (tid < 64) {
        const int b = tid >> 3, jq = (tid & 7) * 4;
        const float4 hb = *(const float4*)&Xb[b][jbase + jq];
        const bool live = (t < Lens[b]);
        float4 r = hb;
        if (live) {
          const float4 p0 = *(const float4*)&Xpart[b][jq + 0][0];
          const float4 p1 = *(const float4*)&Xpart[b][jq + 1][0];
          const float4 p2 = *(const float4*)&Xpart[b][jq + 2][0];
          const float4 p3 = *(const float4*)&Xpart[b][jq + 3][0];
          r.x = tanh_fast(p0.x + p0.y + p0.z + p0.w + bias4.x);
          r.y = tanh_fast(p1.x + p1.y + p1.z + p1.w + bias4.y);
          r.z = tanh_fast(p2.x + p2.y + p2.z + p2.w + bias4.z);
          r.w = tanh_fast(p3.x + p3.y + p3.z + p3.w + bias4.w);
        }
        double* dst = layer ? ((double*)h1r + (size_t)cur * (SLOT / 2))
                            : ((double*)h0r + (size_t)wr0 * (SLOT / 2));
        const size_t di = (size_t)(bbase + b) * 256 + ((jbase + jq) >> 1);
        st2(&dst[di],     make_float2(r.x, r.y));
        st2(&dst[di + 1], make_float2(r.z, r.w));
        if (p == plast) {   // fused epilogue: own tile = own output
          if (layer == 0) {
            *(float4*)&out[32768 + (size_t)(bbase + b) * 1024 + jbase + jq] = r;
          } else {
            *(float4*)&out[(size_t)(bbase + b) * 512 + jbase + jq] = r;
            *(float4*)&out[32768 + (size_t)(bbase + b) * 1024 + 512 + jbase + jq] = r;
          }
        }
      }
    }

    // ---- exchange: drain -> dual flag publish -> prefetch -> detect ----
    // Ring data is written and drained exclusively by wave 0; flag publish
    // needs only wave0's vmcnt(0). Dual publish: sc0 (fast venue) + sc1
    // (proven venue). Data visibility (MALL) is guaranteed by the drain
    // BEFORE either flag is observable -> placement-independent correctness.
    WAIT_VM0();
    if (tid == 0 && active) { // l0 publishes p+1 slots, l1 publishes p
      const u32 fv = (u32)(layer ? p : (p + 1));
      st_flag_sc0(Gown, fv);
      __hip_atomic_store(Fown, fv, __ATOMIC_RELAXED, __HIP_MEMORY_SCOPE_AGENT);
    }
    __syncthreads();
    const int np = p + 1;
    if (layer == 0 && np <= plast) {
      #pragma unroll
      for (int i = 0; i < 4; ++i) {
        const int u = tid + NTHR * i;
        const int r = u >> 7, c = (u & 127) * 4;
        const int tok = x[(bbase + r) * SEQ + np];
        pf[i] = *(const float4*)&emb[(size_t)tok * HID + c];
      }
    }
    if (np <= P) {
      if (tid < 64) {
        u32* fpF = Fown;            // dummies for idle lanes (always valid)
        u32* fpG = Gown;
        u32  tgt = 0;
        bool ok  = true;            // idle lanes start satisfied
        if (lane < 16) {
          fpF = F0 + lane * 32; fpG = G0 + lane * 32; tgt = (u32)np; ok = false;
        } else if (lane < 32) {
          if (layer) {
            fpF = F1 + (lane - 16) * 32; fpG = G1 + (lane - 16) * 32;
            tgt = (u32)(np - 1); ok = false;
          } else {
            const int th = np + 1 - ring;   // ring WAR throttle
            if (th > 0) {
              fpF = F1 + (lane - 16) * 32; fpG = G1 + (lane - 16) * 32;
              tgt = (u32)th; ok = false;
            }
          }
        }
        // latched hybrid poll: fast venue (sc0, XCD-L2) normally; proven
        // venue (sc1, MALL) every 4th iteration as the cross-XCD rescue.
        int k = 0;
        while (true) {
          if (!ok) {
            const u32 vv = ((k & 3) == 3)
                ? __hip_atomic_load(fpF, __ATOMIC_RELAXED,
                                    __HIP_MEMORY_SCOPE_AGENT)
                : ld_flag_sc0(fpG);
            ok = (vv >= tgt);
          }
          if (__ballot(ok) == ~0ull) break;
          __builtin_amdgcn_s_sleep(1);
          ++k;
        }
      }
      __syncthreads();
    }
    prev = cur; cur = wr0;
  }
}

extern "C" void kernel_launch(void* const* d_in, const int* in_sizes, int n_in,
                              void* d_out, int out_size, void* d_ws, size_t ws_size,
                              hipStream_t stream) {
  (void)in_sizes; (void)n_in; (void)out_size; (void)ws_size;
  const int*   x       = (const int*)d_in[0];
  const int*   lengths = (const int*)d_in[1];
  const float* emb     = (const float*)d_in[2];
  const float* W_ih    = (const float*)d_in[3];
  const float* W_hh    = (const float*)d_in[4];
  const float* b_ih    = (const float*)d_in[5];
  const float* b_hh    = (const float*)d_in[6];
  float* out = (float*)d_out;

  const size_t slotB = (size_t)SLOT * sizeof(float);   // 128KB
  const int ring = RING;                               // 8: MALL-resident

  float* h0r = (float*)d_ws;
  float* h1r = h0r + (size_t)ring * SLOT;
  u32*   F   = (u32*)(h1r + (size_t)ring * SLOT);

  // zero slot 0 of each ring (h(-1)=0) + F (32KB) and G (at +64KB) flag
  // regions; kernel-launch acquire invalidates any stale G lines in L2s.
  hipMemsetAsync(h0r, 0, slotB, stream);
  hipMemsetAsync(h1r, 0, slotB, stream);
  hipMemsetAsync(F, 0, 131072, stream);

  hipLaunchKernelGGL(rnn_persistent, dim3(256), dim3(NTHR), 0, stream,
                     x, lengths, emb, W_ih, W_hh, b_ih, b_hh, out,
                     h0r, h1r, F, ring);
}